// Round 11
// baseline (32.319 us; speedup 1.0000x reference)
//
#include <hip/hip_runtime.h>
#include <type_traits>

typedef __attribute__((ext_vector_type(4))) float f32x4;
typedef __attribute__((ext_vector_type(8))) short s16x8;

__device__ __forceinline__ unsigned short f2bf(float f) {
    unsigned int u = __builtin_bit_cast(unsigned int, f);
    u += 0x7fffu + ((u >> 16) & 1u);           // round-to-nearest-even
    return (unsigned short)(u >> 16);
}

// packed f32x2 -> bf16x2 (RNE), one HW instr
__device__ __forceinline__ unsigned cvtpk(float lo, float hi) {
    unsigned r;
    asm("v_cvt_pk_bf16_f32 %0, %1, %2" : "=v"(r) : "v"(lo), "v"(hi));
    return r;
}

__device__ __forceinline__ void gload_lds16(const void* g, void* l) {
    __builtin_amdgcn_global_load_lds(
        (const __attribute__((address_space(1))) void*)g,
        (__attribute__((address_space(3))) void*)l, 16, 0, 0);
}

// ---------------------------------------------------------------------------
// LDS tile section (bf16, 64 k-elems = 128 B per row):
//   byte(row, chunk) = row*128 + ((chunk ^ (row&7)) << 4)
// Staged via global_load_lds: linear LDS dest, pre-swizzled source chunk.
// ---------------------------------------------------------------------------
template<int ROWS, int WAVES>
__device__ __forceinline__ void stage_lds(const unsigned short* __restrict__ src,
                                          int ld, int row0, int k0,
                                          char* lds, int wid, int lane) {
    const int subrow = lane >> 3;            // 0..7
    const int gchunk = (lane & 7) ^ subrow;  // inverse swizzle on source
    #pragma unroll
    for (int p = 0; p < ROWS / (WAVES * 8); ++p) {
        const int r0 = (p * WAVES + wid) * 8;
        const int gr = row0 + r0 + subrow;
        const char* g = (const char*)(src + (size_t)gr * ld + k0) + gchunk * 16;
        gload_lds16(g, lds + r0 * 128);      // wave-uniform base + lane*16
    }
}

__device__ __forceinline__ int xcd_swizzle(int bid, int nwg) {
    const int q = nwg >> 3, r = nwg & 7;
    const int xcd = bid & 7, idx = bid >> 3;
    return (xcd < r ? xcd * (q + 1) : r * (q + 1) + (xcd - r) * q) + idx;
}

// ---------------------------------------------------------------------------
// K1: blocks [0,256): fused prep+GEMM1 — C1[512,512] = bf16(x @ W), 32x32
//     tiles, BK=128/phase, 8 phases, in-kernel cvt_pk + W-transpose, T14 dbuf.
//     blocks [256,504): E-warm — pre-touch E[:,0:128] (10 MB = the first two
//     gemm2 K-step footprints for every panel) into L2/L3, concurrent with
//     the g1 compute. Fill kernels thrash L3 between replays (268 MB/replay),
//     so E is HBM-cold at gemm2 start without this.
// ---------------------------------------------------------------------------
__global__ __launch_bounds__(256) void fused_g1(const float* __restrict__ x,
                                                const float* __restrict__ W,
                                                const float* __restrict__ E,
                                                unsigned short* __restrict__ C1) {
    constexpr int SEC = 4096;                  // one 64-k section: 32 rows * 128 B
    constexpr int PBUF = 4 * SEC;              // phase buf: A(2 sec) + B(2 sec)
    __shared__ __align__(16) char lds[2 * PBUF];   // 32 KiB

    const int tid = threadIdx.x;

    if (blockIdx.x >= 256) {                   // ---- E-warm branch
        const int w = (int)blockIdx.x - 256;   // 0..247
        float s = 0.f;
        #pragma unroll
        for (int i = 0; i < 6; ++i) {
            const int r = w * 81 + i * 16 + (tid >> 4);
            if (r < 20000) {
                #pragma unroll
                for (int j = 0; j < 2; ++j) {
                    const f32x4 v = *reinterpret_cast<const f32x4*>(
                        E + (size_t)r * 512 + j * 64 + (tid & 15) * 4);
                    s += v.x + v.y + v.z + v.w;
                }
            }
        }
        asm volatile("" :: "v"(s));            // keepalive (rule 17) — no DCE
        return;
    }

    const int bid = xcd_swizzle((int)blockIdx.x, 256);
    const int m0 = (bid & 15) * 32, n0 = (bid >> 4) * 32;

    const int lane = tid & 63, wid = tid >> 6;
    const int wm = wid >> 1, wn = wid & 1;
    const int lr = lane & 15, lg = lane >> 4;

    const int rowA = tid >> 3, ksA = (tid & 7) * 16;   // A: 32 rows x 16 k / thread
    const int nB = tid & 31,  ksB = (tid >> 5) * 16;   // B: 32 cols x 16 k / thread

    f32x4 acc = {0.f, 0.f, 0.f, 0.f};
    f32x4 va[4];
    float wb[16];

    auto loadPh = [&](int k0) {
        const float* pa = x + (size_t)(m0 + rowA) * 1024 + k0 + ksA;
        #pragma unroll
        for (int i = 0; i < 4; ++i) va[i] = *reinterpret_cast<const f32x4*>(pa + i * 4);
        #pragma unroll
        for (int i = 0; i < 16; ++i) wb[i] = W[(size_t)(k0 + ksB + i) * 512 + n0 + nB];
    };
    auto writePh = [&](char* buf) {
        uint4 u0 = { cvtpk(va[0].x,va[0].y), cvtpk(va[0].z,va[0].w),
                     cvtpk(va[1].x,va[1].y), cvtpk(va[1].z,va[1].w) };
        uint4 u1 = { cvtpk(va[2].x,va[2].y), cvtpk(va[2].z,va[2].w),
                     cvtpk(va[3].x,va[3].y), cvtpk(va[3].z,va[3].w) };
        {
            const int sec = ksA >> 6, cin = (ksA & 63) >> 3;
            char* base = buf + sec * SEC + rowA * 128;
            *reinterpret_cast<uint4*>(base + ((( cin    ) ^ (rowA & 7)) << 4)) = u0;
            *reinterpret_cast<uint4*>(base + (((cin + 1) ^ (rowA & 7)) << 4)) = u1;
        }
        uint4 w0 = { cvtpk(wb[0],wb[1]),  cvtpk(wb[2],wb[3]),
                     cvtpk(wb[4],wb[5]),  cvtpk(wb[6],wb[7]) };
        uint4 w1 = { cvtpk(wb[8],wb[9]),  cvtpk(wb[10],wb[11]),
                     cvtpk(wb[12],wb[13]), cvtpk(wb[14],wb[15]) };
        {
            const int sec = ksB >> 6, cin = (ksB & 63) >> 3;
            char* base = buf + 2 * SEC + sec * SEC + nB * 128;
            *reinterpret_cast<uint4*>(base + ((( cin    ) ^ (nB & 7)) << 4)) = w0;
            *reinterpret_cast<uint4*>(base + (((cin + 1) ^ (nB & 7)) << 4)) = w1;
        }
    };

    loadPh(0);
    writePh(lds);
    __syncthreads();

    #pragma unroll 1
    for (int ph = 0; ph < 8; ++ph) {
        char* cur = lds + (ph & 1) * PBUF;
        char* nxt = lds + ((ph + 1) & 1) * PBUF;
        if (ph < 7) loadPh((ph + 1) * 128);            // loads in flight over compute
        #pragma unroll
        for (int sec = 0; sec < 2; ++sec) {
            const char* As = cur + sec * SEC;
            const char* Bs = cur + 2 * SEC + sec * SEC;
            #pragma unroll
            for (int kk = 0; kk < 2; ++kk) {
                const int c = kk * 4 + lg;
                const int ra = wm * 16 + lr, rb = wn * 16 + lr;
                s16x8 a = *reinterpret_cast<const s16x8*>(As + ra * 128 + ((c ^ (ra & 7)) << 4));
                s16x8 b = *reinterpret_cast<const s16x8*>(Bs + rb * 128 + ((c ^ (rb & 7)) << 4));
                acc = __builtin_amdgcn_mfma_f32_16x16x32_bf16(a, b, acc, 0, 0, 0);
            }
        }
        if (ph < 7) writePh(nxt);                      // cvt+ds_write late (T14)
        __syncthreads();
    }

    const int gcol = n0 + wn * 16 + lr;                // C/D: col=lane&15 [m89]
    const int grow0 = m0 + wm * 16 + lg * 4;
    #pragma unroll
    for (int r = 0; r < 4; ++r)
        C1[(size_t)(grow0 + r) * 512 + gcol] = f2bf(acc[r]);
}

// ---------------------------------------------------------------------------
// K2: GEMM2  out[512,20000] = C1 @ E^T (f32). Tile 128x160, BK=64, 8 K-steps.
// 512 threads = 8 waves (4m x 2n; per-wave 32x80, MF=2 NF=5) -> 72 KiB LDS,
// <=128 VGPR, 2 blocks/CU = 16 waves/CU (4/SIMD).
// A (C1 bf16): global_load_lds (2/wave/step).  B (E f32): coalesced global ->
// regs (5 dwordx4/thread) -> cvt_pk -> ds_write into freed buffer (T14).
// One raw s_barrier per K-step; counted vmcnt (B stays in flight across it).
// Ledger/iter t: entry outstanding A(t)=2; +B(t+1)=5 -> 7; vmcnt(5) drains
// A(t); lgkm(0) publishes my B(t) ds_writes; s_barrier => tile t complete,
// nxt free; +A(t+1)=2; compute cur; writeB(t+1)->nxt (compiler drains B regs).
// Grid 504 = 8 XCDs x {63,63,63,63,62,62,62,62}; 20000 = 125*160, no N edge.
// ---------------------------------------------------------------------------
__global__ __launch_bounds__(512, 4) void gemm2fused(const unsigned short* __restrict__ C1,
                                                     const float* __restrict__ E,
                                                     float* __restrict__ out) {
    constexpr int MF = 2, NF = 5, BM = 128, BN = 160;
    constexpr int N = 20000, K = 512, NSTEP = K / 64;
    constexpr int ABUF = BM * 128;                 // 16384
    constexpr int BUF = (BM + BN) * 128;           // 36864
    __shared__ __align__(16) char lds[2 * BUF];    // 72 KiB

    const int xcd = (int)blockIdx.x & 7, idx = (int)blockIdx.x >> 3;
    if (xcd >= 4 && idx >= 62) return;
    const int nb = (xcd < 4 ? xcd * 63 : 252 + (xcd - 4) * 62) + idx;
    const int m0 = (nb & 3) * BM;                  // 4 consecutive nb share E panel
    const int n0 = (nb >> 2) * BN;

    const int tid = threadIdx.x, lane = tid & 63, wid = tid >> 6;  // 0..7
    const int wm = wid >> 1, wn = wid & 1;         // 4 x 2 wave grid
    const int arow_base = wm * 32;                 // 0/32/64/96
    const int brow_base = wn * 80;                 // 0/80
    const int lr = lane & 15, lg = lane >> 4;

    const int r_in = tid >> 4, c4 = tid & 15;      // B stage: 32 row-slots x 16

    f32x4 acc[MF][NF] = {};
    f32x4 breg[5];

    auto loadB = [&](int k0) {
        #pragma unroll
        for (int p = 0; p < 5; ++p)
            breg[p] = *reinterpret_cast<const f32x4*>(
                E + (size_t)(n0 + p * 32 + r_in) * 512 + k0 + c4 * 4);
    };
    auto writeB = [&](char* Bs) {
        #pragma unroll
        for (int p = 0; p < 5; ++p) {
            const int row = p * 32 + r_in;
            const unsigned lo = cvtpk(breg[p].x, breg[p].y);
            const unsigned hi = cvtpk(breg[p].z, breg[p].w);
            const int byte = row * 128 + (((c4 >> 1) ^ (row & 7)) << 4) + (c4 & 1) * 8;
            *reinterpret_cast<uint2*>(Bs + byte) = make_uint2(lo, hi);
        }
    };

    loadB(0);                                          // vm: B0=5
    stage_lds<BM, 8>(C1, K, m0, 0, lds, wid, lane);    // vm: +A0=2 -> 7
    writeB(lds + ABUF);                                // compiler waits breg only

    #pragma unroll 1
    for (int t = 0; t < NSTEP; ++t) {
        char* cur = lds + (t & 1) * BUF;
        char* nxt = lds + ((t + 1) & 1) * BUF;
        if (t < NSTEP - 1) {
            loadB((t + 1) * 64);                       // B(t+1) regs, in flight
            asm volatile("s_waitcnt vmcnt(5)" ::: "memory");   // A(t) landed
        } else {
            asm volatile("s_waitcnt vmcnt(0)" ::: "memory");
        }
        asm volatile("s_waitcnt lgkmcnt(0)" ::: "memory");     // publish ds_writes
        __builtin_amdgcn_s_barrier();                  // tile t complete; nxt free
        if (t < NSTEP - 1)
            stage_lds<BM, 8>(C1, K, m0, (t + 1) * 64, nxt, wid, lane);  // A(t+1)

        // compute tile t: kk-halves interleaved to keep frag regs low
        #pragma unroll
        for (int kk = 0; kk < 2; ++kk) {
            const int c = kk * 4 + lg;
            s16x8 af[MF], bfr[NF];
            #pragma unroll
            for (int f = 0; f < MF; ++f) {
                const int row = arow_base + f * 16 + lr;
                af[f] = *reinterpret_cast<const s16x8*>(cur + row * 128 + ((c ^ (row & 7)) << 4));
            }
            #pragma unroll
            for (int f = 0; f < NF; ++f) {
                const int row = brow_base + f * 16 + lr;
                bfr[f] = *reinterpret_cast<const s16x8*>(cur + ABUF + row * 128 + ((c ^ (row & 7)) << 4));
            }
            __builtin_amdgcn_s_setprio(1);
            #pragma unroll
            for (int mi = 0; mi < MF; ++mi)
                #pragma unroll
                for (int ni = 0; ni < NF; ++ni)
                    acc[mi][ni] = __builtin_amdgcn_mfma_f32_16x16x32_bf16(
                        af[mi], bfr[ni], acc[mi][ni], 0, 0, 0);
            __builtin_amdgcn_s_setprio(0);
        }

        if (t < NSTEP - 1)
            writeB(nxt + ABUF);                        // cvt+write B(t+1) (late)
    }

    // epilogue: C/D layout col = lane&15, row = (lane>>4)*4 + reg   [m89]
    #pragma unroll
    for (int mi = 0; mi < MF; ++mi)
        #pragma unroll
        for (int ni = 0; ni < NF; ++ni) {
            const int gcol = n0 + brow_base + ni * 16 + lr;
            const int grow0 = m0 + arow_base + mi * 16 + lg * 4;
            #pragma unroll
            for (int r = 0; r < 4; ++r)
                out[(size_t)(grow0 + r) * N + gcol] = acc[mi][ni][r];
        }
}

// ---------------------------------------------------------------------------

extern "C" void kernel_launch(void* const* d_in, const int* in_sizes, int n_in,
                              void* d_out, int out_size, void* d_ws, size_t ws_size,
                              hipStream_t stream) {
    const float* x = (const float*)d_in[0];     // [512,1024]
    const float* E = (const float*)d_in[1];     // [20000,512]
    const float* W = (const float*)d_in[2];     // [1024,512]
    float* out = (float*)d_out;                 // [512,20000]

    unsigned short* C1 = (unsigned short*)d_ws; // 512 KiB

    // K1: fused prep + GEMM1 (256 blocks) + E[:,0:128] warm (248 blocks)
    fused_g1<<<504, 256, 0, stream>>>(x, W, E, C1);

    // K2: out = C1 @ E^T, 8-wave blocks, 504 launched (500 real)
    gemm2fused<<<504, 512, 0, stream>>>(C1, E, out);
}